// Round 2
// baseline (375.539 us; speedup 1.0000x reference)
//
#include <hip/hip_runtime.h>
#include <math.h>

// Problem constants
#define B_N   16
#define C_CH  192
#define HW    16384          // 128*128
// LUT config: x in [-8, 8], step 1/128
#define LUT_INTERVALS 2048
#define LUT_NODES     (LUT_INTERVALS + 1)
#define LUT_XMIN      (-8.0f)
#define LUT_INV_STEP  128.0f

// Per-channel pair table: entry i holds (p[i], p[i+1]) so interpolation is one b64 read.
__device__ float2 g_lut2[C_CH * LUT_INTERVALS];   // 3 MB static device memory

__device__ __forceinline__ float sp_f(float x) {
    // softplus, accurate for the small param range (|x| < ~3)
    return log1pf(expf(x));
}

// ---------------------------------------------------------------------------
// Kernel 1: build per-channel LUT of p(x) = F(x+0.5) - F(x-0.5) exactly.
// Tiny: 192 blocks x 2049 nodes x 2 CDF evals.
// ---------------------------------------------------------------------------
__global__ __launch_bounds__(256) void balle_lut_kernel(
    const float* __restrict__ h0, const float* __restrict__ h1,
    const float* __restrict__ h2, const float* __restrict__ h3,
    const float* __restrict__ a0, const float* __restrict__ a1,
    const float* __restrict__ a2,
    const float* __restrict__ b0, const float* __restrict__ b1,
    const float* __restrict__ b2, const float* __restrict__ b3)
{
    const int c = blockIdx.x;
    __shared__ float pg[LUT_NODES];

    // Transformed per-channel params (redundant per thread; kernel is tiny).
    float w0[3], w3[3], ta0[3], ta1[3], ta2[3], c0[3], c1[3], c2[3];
    float w1[9], w2[9];
    #pragma unroll
    for (int r = 0; r < 3; ++r) {
        w0[r]  = sp_f(h0[c * 3 + r]);       // h0: (C,1,R)
        w3[r]  = sp_f(h3[c * 3 + r]);       // h3: (C,R,1)
        ta0[r] = tanhf(a0[c * 3 + r]);
        ta1[r] = tanhf(a1[c * 3 + r]);
        ta2[r] = tanhf(a2[c * 3 + r]);
        c0[r]  = b0[c * 3 + r];
        c1[r]  = b1[c * 3 + r];
        c2[r]  = b2[c * 3 + r];
    }
    #pragma unroll
    for (int k = 0; k < 9; ++k) {
        w1[k] = sp_f(h1[c * 9 + k]);        // h1[c][d][r] = h1[c*9 + d*3 + r]
        w2[k] = sp_f(h2[c * 9 + k]);
    }
    const float c3 = b3[c];                 // b3: (C,1)

    for (int i = threadIdx.x; i < LUT_NODES; i += blockDim.x) {
        const float xg = LUT_XMIN + (float)i * (1.0f / LUT_INV_STEP);
        float p = 0.0f;
        #pragma unroll
        for (int s = 0; s < 2; ++s) {
            const float t = xg + (s == 0 ? 0.5f : -0.5f);
            float v[3], u[3];
            // layer 0: 1 -> 3, einsum out[r] = t * w0[r]
            #pragma unroll
            for (int r = 0; r < 3; ++r) {
                float z = fmaf(t, w0[r], c0[r]);
                v[r] = z + ta0[r] * tanhf(z);
            }
            // layer 1: 3 -> 3, out[r] = sum_d v[d] * w1[d][r]
            #pragma unroll
            for (int r = 0; r < 3; ++r) {
                float z = c1[r];
                #pragma unroll
                for (int d = 0; d < 3; ++d) z = fmaf(v[d], w1[d * 3 + r], z);
                u[r] = z + ta1[r] * tanhf(z);
            }
            // layer 2: 3 -> 3
            #pragma unroll
            for (int r = 0; r < 3; ++r) {
                float z = c2[r];
                #pragma unroll
                for (int d = 0; d < 3; ++d) z = fmaf(u[d], w2[d * 3 + r], z);
                v[r] = z + ta2[r] * tanhf(z);
            }
            // layer 3: 3 -> 1, then sigmoid
            float zs = c3;
            #pragma unroll
            for (int d = 0; d < 3; ++d) zs = fmaf(v[d], w3[d], zs);
            const float F = 1.0f / (1.0f + expf(-zs));
            p += (s == 0 ? F : -F);
        }
        pg[i] = p;
    }
    __syncthreads();
    // Write duplicated-pair table
    for (int i = threadIdx.x; i < LUT_INTERVALS; i += blockDim.x) {
        g_lut2[c * LUT_INTERVALS + i] = make_float2(pg[i], pg[i + 1]);
    }
}

// ---------------------------------------------------------------------------
// Kernel 2: memory-bound elementwise LUT interpolation.
// Each block handles 8192 contiguous elements (half of one (b,c) slice),
// so the channel is block-uniform. LUT staged in LDS (16 KB).
// ---------------------------------------------------------------------------
#define ELEMS_PER_BLOCK 8192
#define THREADS 256
#define ITERS (ELEMS_PER_BLOCK / (THREADS * 4))   // 8 float4 iters per thread

__global__ __launch_bounds__(THREADS) void balle_main_kernel(
    const float* __restrict__ x, float* __restrict__ out)
{
    __shared__ float2 slut[LUT_INTERVALS];
    const int blk = blockIdx.x;
    const int c = (blk >> 1) % C_CH;   // base/HW % C, with 2 blocks per slice

    const float2* __restrict__ gl = g_lut2 + c * LUT_INTERVALS;
    for (int i = threadIdx.x; i < LUT_INTERVALS; i += THREADS) slut[i] = gl[i];
    __syncthreads();

    const long long base = (long long)blk * ELEMS_PER_BLOCK;
    const float4* __restrict__ xin = (const float4*)(x + base);
    float4* __restrict__ po = (float4*)(out + base);

    #pragma unroll
    for (int it = 0; it < ITERS; ++it) {
        const int idx = it * THREADS + threadIdx.x;
        const float4 v = xin[idx];
        float vv[4] = {v.x, v.y, v.z, v.w};
        float rr[4];
        #pragma unroll
        for (int j = 0; j < 4; ++j) {
            float u = (vv[j] - LUT_XMIN) * LUT_INV_STEP;
            u = fminf(fmaxf(u, 0.0f), 2047.99f);
            int i0 = (int)u;
            if (i0 > LUT_INTERVALS - 1) i0 = LUT_INTERVALS - 1;
            const float f = u - (float)i0;
            const float2 p2 = slut[i0];
            rr[j] = fmaf(f, p2.y - p2.x, p2.x);
        }
        float4 r;
        r.x = rr[0]; r.y = rr[1]; r.z = rr[2]; r.w = rr[3];
        po[idx] = r;
    }
}

extern "C" void kernel_launch(void* const* d_in, const int* in_sizes, int n_in,
                              void* d_out, int out_size, void* d_ws, size_t ws_size,
                              hipStream_t stream) {
    const float* x  = (const float*)d_in[0];
    const float* h0 = (const float*)d_in[1];
    const float* h1 = (const float*)d_in[2];
    const float* h2 = (const float*)d_in[3];
    const float* h3 = (const float*)d_in[4];
    const float* a0 = (const float*)d_in[5];
    const float* a1 = (const float*)d_in[6];
    const float* a2 = (const float*)d_in[7];
    const float* b0 = (const float*)d_in[8];
    const float* b1 = (const float*)d_in[9];
    const float* b2 = (const float*)d_in[10];
    const float* b3 = (const float*)d_in[11];
    float* out = (float*)d_out;

    balle_lut_kernel<<<C_CH, 256, 0, stream>>>(h0, h1, h2, h3, a0, a1, a2,
                                               b0, b1, b2, b3);

    const int total = B_N * C_CH * HW;            // 50,331,648
    const int grid = total / ELEMS_PER_BLOCK;     // 6144
    balle_main_kernel<<<grid, THREADS, 0, stream>>>(x, out);
}